// Round 11
// baseline (540.652 us; speedup 1.0000x reference)
//
#include <hip/hip_runtime.h>

#define AS1 __attribute__((address_space(1)))
#define AS3 __attribute__((address_space(3)))

typedef __attribute__((ext_vector_type(8))) short short8;
typedef __attribute__((ext_vector_type(4))) float floatx4;

__device__ __forceinline__ float b2f(ushort u) {
  union { unsigned int i; float f; } x; x.i = ((unsigned int)u) << 16; return x.f;
}
__device__ __forceinline__ ushort f2b(float f) {
  union { float f; unsigned int i; } x; x.f = f;
  unsigned int r = (x.i + 0x7fffu + ((x.i >> 16) & 1u)) >> 16;
  return (ushort)r;
}

#define GF_RELU 1

// ---------------------------------------------------------------------------
// v11 = v10 with the compile fix: LDS double-buffer pointers computed via
// offset arithmetic per iteration (a local const array of addrspace(3)
// pointers was rejected by gfx950 codegen: "unsupported expression in
// static initializer: addrspacecast").
//
// v10 theory (untested, stands): 2-phase double-buffered prefetch on every
// heavy GEMM (qk_exp, pv_wu, FF1/FF2, qkv):
//   prologue: stage(buf0); barrier
//   iter t:   issue stage(t+1 -> buf^1); ds_read+MFMA on buf; barrier
// One barrier/K-step (was 2); staging latency hides under compute. LDS 64KB
// (buf0: A@0,B@8192; buf1: A@16384,B@24576 in ushort units), bounce epilogue
// aliases it after the final barrier; 2 blocks/CU preserved.
// ---------------------------------------------------------------------------

// Pass A: VWt[b][c][j] = sum_d Wu[d][c] * V[b][j][d].  (tiny; BK=32 skeleton)
__global__ __launch_bounds__(256) void gemm_vw(
    const ushort* __restrict__ qkv, const ushort* __restrict__ wut,
    ushort* __restrict__ vwt)
{
  __shared__ __align__(16) ushort As[128 * 32];
  __shared__ __align__(16) ushort Bs[128 * 32];

  const int id = blockIdx.x;
  const int b  = id >> 7;
  const int t  = id & 127;
  const int bx = t & 31;              // j tile
  const int by = t >> 5;              // c tile

  const ushort* A  = wut;
  const ushort* Bt = qkv + (size_t)b * 4096 * 1536 + 1024;
  ushort* C = vwt + (size_t)b * 512 * 4096;

  const int tid  = threadIdx.x;
  const int w    = tid >> 6;
  const int lane = tid & 63;
  const int lo   = lane & 15;
  const int quad = lane >> 4;
  const int m0   = by * 128;
  const int n0   = bx * 128;
  const int wm   = (w & 1) * 64;
  const int wn   = (w >> 1) * 64;

  const int i0 = tid, i1 = tid + 256;
  const ushort* ga0 = A  + (size_t)(m0 + (i0 >> 2)) * 512 + ((i0 & 3) << 3);
  const ushort* ga1 = A  + (size_t)(m0 + (i1 >> 2)) * 512 + ((i1 & 3) << 3);
  const ushort* gb0 = Bt + (size_t)(n0 + (i0 >> 2)) * 1536 + ((i0 & 3) << 3);
  const ushort* gb1 = Bt + (size_t)(n0 + (i1 >> 2)) * 1536 + ((i1 & 3) << 3);

  floatx4 acc[4][4] = {};

  for (int k0 = 0; k0 < 512; k0 += 32) {
    __syncthreads();
    __builtin_amdgcn_global_load_lds((const AS1 void*)(ga0 + k0), (AS3 void*)(As + i0 * 8), 16, 0, 0);
    __builtin_amdgcn_global_load_lds((const AS1 void*)(ga1 + k0), (AS3 void*)(As + i1 * 8), 16, 0, 0);
    __builtin_amdgcn_global_load_lds((const AS1 void*)(gb0 + k0), (AS3 void*)(Bs + i0 * 8), 16, 0, 0);
    __builtin_amdgcn_global_load_lds((const AS1 void*)(gb1 + k0), (AS3 void*)(Bs + i1 * 8), 16, 0, 0);
    __syncthreads();

    short8 af[4], bf[4];
#pragma unroll
    for (int tt = 0; tt < 4; ++tt) {
      af[tt] = *(const short8*)(As + (wm + tt * 16 + lo) * 32 + quad * 8);
      bf[tt] = *(const short8*)(Bs + (wn + tt * 16 + lo) * 32 + quad * 8);
    }
#pragma unroll
    for (int mt = 0; mt < 4; ++mt)
#pragma unroll
      for (int nt = 0; nt < 4; ++nt)
        acc[mt][nt] = __builtin_amdgcn_mfma_f32_16x16x32_bf16(af[mt], bf[nt], acc[mt][nt], 0, 0, 0);
  }

#pragma unroll
  for (int mt = 0; mt < 4; ++mt)
#pragma unroll
    for (int nt = 0; nt < 4; ++nt)
#pragma unroll
      for (int r = 0; r < 4; ++r) {
        const int row = m0 + wm + mt * 16 + quad * 4 + r;
        const int col = n0 + wn + nt * 16 + lo;
        C[(size_t)row * 4096 + col] = f2b(acc[mt][nt][r]);
      }
}

// Pass B: P = exp((Q.K^T)/8). 2-phase dbuf staging + LDS-bounce epilogue.
// XCD rectangle map (v9-proven): xcd owns (batch, by-half) x all bx.
__global__ __launch_bounds__(256) void gemm_qk_exp(
    const ushort* __restrict__ qkv, ushort* __restrict__ P)
{
  __shared__ __align__(16) ushort smem[4 * 128 * 64];  // buf0 A|B, buf1 A|B

  const int id  = blockIdx.x;         // 0..4095
  const int xcd = id & 7;
  const int s   = id >> 3;            // 0..511
  const int b   = xcd >> 1;           // batch
  const int by  = (xcd & 1) * 16 + (s & 15);
  const int bx  = s >> 4;             // 0..31

  const ushort* A  = qkv + (size_t)b * 4096 * 1536;        // Q rows
  const ushort* Bt = qkv + (size_t)b * 4096 * 1536 + 512;  // K rows
  ushort* C = P + (size_t)b * 4096 * 4096;

  const int tid  = threadIdx.x;
  const int w    = tid >> 6;
  const int lane = tid & 63;
  const int lo   = lane & 15;
  const int quad = lane >> 4;
  const int m0   = by * 128;
  const int n0   = bx * 128;
  const int wm   = (w & 1) * 64;
  const int wn   = (w >> 1) * 64;

  const ushort* gaP[4]; const ushort* gbP[4];
#pragma unroll
  for (int k = 0; k < 4; ++k) {
    const int s_ = tid + k * 256;
    const int row = s_ >> 3, sl = s_ & 7;
    gaP[k] = A  + (size_t)(m0 + row) * 1536 + ((sl ^ (row & 7)) << 3);
    gbP[k] = Bt + (size_t)(n0 + row) * 1536 + ((sl ^ (row & 7)) << 3);
  }

  floatx4 acc[4][4] = {};

  // Prologue: stage tile 0 into buf0.
#pragma unroll
  for (int k = 0; k < 4; ++k) {
    const int s_ = tid + k * 256;
    __builtin_amdgcn_global_load_lds((const AS1 void*)(gaP[k]), (AS3 void*)(smem + s_ * 8), 16, 0, 0);
    __builtin_amdgcn_global_load_lds((const AS1 void*)(gbP[k]), (AS3 void*)(smem + 8192 + s_ * 8), 16, 0, 0);
  }
  __syncthreads();

  for (int it = 0; it < 8; ++it) {
    const int bo = (it & 1) << 14;    // 0 or 16384 (ushort units)
    const ushort* Ac = smem + bo;
    const ushort* Bc = smem + bo + 8192;
    if (it < 7) {                     // issue next-tile stage before compute
      const int bn = ((it & 1) ^ 1) << 14;
      ushort* An = smem + bn;
      ushort* Bn = smem + bn + 8192;
      const int k0n = (it + 1) * 64;
#pragma unroll
      for (int k = 0; k < 4; ++k) {
        const int s_ = tid + k * 256;
        __builtin_amdgcn_global_load_lds((const AS1 void*)(gaP[k] + k0n), (AS3 void*)(An + s_ * 8), 16, 0, 0);
        __builtin_amdgcn_global_load_lds((const AS1 void*)(gbP[k] + k0n), (AS3 void*)(Bn + s_ * 8), 16, 0, 0);
      }
    }

#pragma unroll
    for (int kk = 0; kk < 2; ++kk) {
      short8 af[4], bf[4];
#pragma unroll
      for (int tt = 0; tt < 4; ++tt) {
        const int ra = wm + tt * 16 + lo;
        const int rb = wn + tt * 16 + lo;
        af[tt] = *(const short8*)(Ac + (size_t)ra * 64 + (((kk * 4 + quad) ^ (ra & 7)) << 3));
        bf[tt] = *(const short8*)(Bc + (size_t)rb * 64 + (((kk * 4 + quad) ^ (rb & 7)) << 3));
      }
#pragma unroll
      for (int mt = 0; mt < 4; ++mt)
#pragma unroll
        for (int nt = 0; nt < 4; ++nt)
          acc[mt][nt] = __builtin_amdgcn_mfma_f32_16x16x32_bf16(af[mt], bf[nt], acc[mt][nt], 0, 0, 0);
    }
    __syncthreads();                  // drains next-tile stage; buf reads done
  }

  // LDS-bounce epilogue (aliases stage buffers; all reads complete).
#pragma unroll
  for (int mt = 0; mt < 4; ++mt)
#pragma unroll
    for (int r = 0; r < 4; ++r) {
      const int row = wm + mt * 16 + quad * 4 + r;
#pragma unroll
      for (int nt = 0; nt < 4; ++nt) {
        const int col = wn + nt * 16 + lo;
        smem[row * 128 + ((((col >> 3) ^ (row & 7)) << 3) | (col & 7))] =
            f2b(__expf(acc[mt][nt][r] * 0.125f));
      }
    }
  __syncthreads();
#pragma unroll
  for (int k = 0; k < 8; ++k) {
    const int c = tid + k * 256;
    const int row = c >> 4, c16 = c & 15;
    const short8 v = *(const short8*)(smem + row * 128 + ((c16 ^ (row & 7)) << 3));
    *(short8*)(C + (size_t)(m0 + row) * 4096 + n0 + c16 * 8) = v;
  }
}

// Pass C: uni = (P @ VWt)/rs + Wu_b, rs inline via mfma(af, ones).
// 2-phase dbuf staging; XCD-panel swizzle (v7/v8-proven).
__global__ __launch_bounds__(256) void gemm_pv_wu(
    const ushort* __restrict__ P, const ushort* __restrict__ vwt,
    const float* __restrict__ bias, ushort* __restrict__ uni)
{
  __shared__ __align__(16) ushort smem[4 * 128 * 64];
  __shared__ float rsm[128];

  const int id  = blockIdx.x;         // 0..511
  const int xcd = id & 7;
  const int s   = id >> 3;            // 0..63
  const int bx  = s & 3;              // col tile
  const int panel = xcd * 16 + (s >> 2);  // 0..127
  const int b  = panel >> 5;
  const int by = panel & 31;

  const ushort* A  = P   + (size_t)b * 4096 * 4096;
  const ushort* Bt = vwt + (size_t)b * 512 * 4096;

  const int tid  = threadIdx.x;
  const int w    = tid >> 6;
  const int lane = tid & 63;
  const int lo   = lane & 15;
  const int quad = lane >> 4;
  const int m0   = by * 128;
  const int n0   = bx * 128;
  const int wm   = (w & 1) * 64;
  const int wn   = (w >> 1) * 64;

  const ushort* gaP[4]; const ushort* gbP[4];
#pragma unroll
  for (int k = 0; k < 4; ++k) {
    const int s_ = tid + k * 256;
    const int row = s_ >> 3, sl = s_ & 7;
    gaP[k] = A  + (size_t)(m0 + row) * 4096 + ((sl ^ (row & 7)) << 3);
    gbP[k] = Bt + (size_t)(n0 + row) * 4096 + ((sl ^ (row & 7)) << 3);
  }

  short8 ones;
#pragma unroll
  for (int j = 0; j < 8; ++j) ones[j] = (short)0x3F80;  // bf16 1.0

  floatx4 acc[4][4] = {};
  floatx4 rsacc[4] = {};

#pragma unroll
  for (int k = 0; k < 4; ++k) {
    const int s_ = tid + k * 256;
    __builtin_amdgcn_global_load_lds((const AS1 void*)(gaP[k]), (AS3 void*)(smem + s_ * 8), 16, 0, 0);
    __builtin_amdgcn_global_load_lds((const AS1 void*)(gbP[k]), (AS3 void*)(smem + 8192 + s_ * 8), 16, 0, 0);
  }
  __syncthreads();

  for (int it = 0; it < 64; ++it) {
    const int bo = (it & 1) << 14;
    const ushort* Ac = smem + bo;
    const ushort* Bc = smem + bo + 8192;
    if (it < 63) {
      const int bn = ((it & 1) ^ 1) << 14;
      ushort* An = smem + bn;
      ushort* Bn = smem + bn + 8192;
      const int k0n = (it + 1) * 64;
#pragma unroll
      for (int k = 0; k < 4; ++k) {
        const int s_ = tid + k * 256;
        __builtin_amdgcn_global_load_lds((const AS1 void*)(gaP[k] + k0n), (AS3 void*)(An + s_ * 8), 16, 0, 0);
        __builtin_amdgcn_global_load_lds((const AS1 void*)(gbP[k] + k0n), (AS3 void*)(Bn + s_ * 8), 16, 0, 0);
      }
    }

#pragma unroll
    for (int kk = 0; kk < 2; ++kk) {
      short8 af[4], bf[4];
#pragma unroll
      for (int tt = 0; tt < 4; ++tt) {
        const int ra = wm + tt * 16 + lo;
        const int rb = wn + tt * 16 + lo;
        af[tt] = *(const short8*)(Ac + (size_t)ra * 64 + (((kk * 4 + quad) ^ (ra & 7)) << 3));
        bf[tt] = *(const short8*)(Bc + (size_t)rb * 64 + (((kk * 4 + quad) ^ (rb & 7)) << 3));
      }
#pragma unroll
      for (int tt = 0; tt < 4; ++tt)
        rsacc[tt] = __builtin_amdgcn_mfma_f32_16x16x32_bf16(af[tt], ones, rsacc[tt], 0, 0, 0);
#pragma unroll
      for (int mt = 0; mt < 4; ++mt)
#pragma unroll
        for (int nt = 0; nt < 4; ++nt)
          acc[mt][nt] = __builtin_amdgcn_mfma_f32_16x16x32_bf16(af[mt], bf[nt], acc[mt][nt], 0, 0, 0);
    }
    __syncthreads();
  }

  if (wn == 0 && lo == 0) {
#pragma unroll
    for (int tt = 0; tt < 4; ++tt)
#pragma unroll
      for (int r = 0; r < 4; ++r)
        rsm[wm + tt * 16 + quad * 4 + r] = rsacc[tt][r];
  }
  __syncthreads();

#pragma unroll
  for (int mt = 0; mt < 4; ++mt)
#pragma unroll
    for (int r = 0; r < 4; ++r) {
      const int lrow = wm + mt * 16 + quad * 4 + r;
      const size_t grow = (size_t)b * 4096 + m0 + lrow;
      const float inv = 1.f / rsm[lrow];
#pragma unroll
      for (int nt = 0; nt < 4; ++nt) {
        const int col = n0 + wn + nt * 16 + lo;
        uni[grow * 512 + col] = f2b(acc[mt][nt][r] * inv + bias[col]);
      }
    }
}

// ---------------------------------------------------------------------------
// Async NT GEMM, 2-phase dbuf staging + LDS-bounce epilogue, flat grid with
// XCD swizzle (FF1 / FF2).
// ---------------------------------------------------------------------------
__global__ __launch_bounds__(256) void gemm_async64(
    const ushort* __restrict__ A, const ushort* __restrict__ Bt,
    const float* __restrict__ bias, ushort* __restrict__ C,
    int N, int K, int lda, int ldb,
    int lg_gx, int lg_gy, float scale, int flags)
{
  __shared__ __align__(16) ushort smem[4 * 128 * 64];

  const int id = blockIdx.x;
  const int r8 = id & 7;
  const int s  = id >> 3;
  const int bx = s & ((1 << lg_gx) - 1);
  const int j  = r8 + ((s >> lg_gx) << 3);
  const int by = j & ((1 << lg_gy) - 1);

  const int tid  = threadIdx.x;
  const int w    = tid >> 6;
  const int lane = tid & 63;
  const int lo   = lane & 15;
  const int quad = lane >> 4;
  const int m0   = by * 128;
  const int n0   = bx * 128;
  const int wm   = (w & 1) * 64;
  const int wn   = (w >> 1) * 64;

  const ushort* gaP[4]; const ushort* gbP[4];
#pragma unroll
  for (int k = 0; k < 4; ++k) {
    const int s_ = tid + k * 256;
    const int row = s_ >> 3, sl = s_ & 7;
    gaP[k] = A  + (size_t)(m0 + row) * lda + ((sl ^ (row & 7)) << 3);
    gbP[k] = Bt + (size_t)(n0 + row) * ldb + ((sl ^ (row & 7)) << 3);
  }

  floatx4 acc[4][4] = {};
  const int nt_ = K >> 6;

#pragma unroll
  for (int k = 0; k < 4; ++k) {
    const int s_ = tid + k * 256;
    __builtin_amdgcn_global_load_lds((const AS1 void*)(gaP[k]), (AS3 void*)(smem + s_ * 8), 16, 0, 0);
    __builtin_amdgcn_global_load_lds((const AS1 void*)(gbP[k]), (AS3 void*)(smem + 8192 + s_ * 8), 16, 0, 0);
  }
  __syncthreads();

  for (int it = 0; it < nt_; ++it) {
    const int bo = (it & 1) << 14;
    const ushort* Ac = smem + bo;
    const ushort* Bc = smem + bo + 8192;
    if (it + 1 < nt_) {
      const int bn = ((it & 1) ^ 1) << 14;
      ushort* An = smem + bn;
      ushort* Bn = smem + bn + 8192;
      const int k0n = (it + 1) * 64;
#pragma unroll
      for (int k = 0; k < 4; ++k) {
        const int s_ = tid + k * 256;
        __builtin_amdgcn_global_load_lds((const AS1 void*)(gaP[k] + k0n), (AS3 void*)(An + s_ * 8), 16, 0, 0);
        __builtin_amdgcn_global_load_lds((const AS1 void*)(gbP[k] + k0n), (AS3 void*)(Bn + s_ * 8), 16, 0, 0);
      }
    }

#pragma unroll
    for (int kk = 0; kk < 2; ++kk) {
      short8 af[4], bf[4];
#pragma unroll
      for (int tt = 0; tt < 4; ++tt) {
        const int ra = wm + tt * 16 + lo;
        const int rb = wn + tt * 16 + lo;
        af[tt] = *(const short8*)(Ac + (size_t)ra * 64 + (((kk * 4 + quad) ^ (ra & 7)) << 3));
        bf[tt] = *(const short8*)(Bc + (size_t)rb * 64 + (((kk * 4 + quad) ^ (rb & 7)) << 3));
      }
#pragma unroll
      for (int mt = 0; mt < 4; ++mt)
#pragma unroll
        for (int nt = 0; nt < 4; ++nt)
          acc[mt][nt] = __builtin_amdgcn_mfma_f32_16x16x32_bf16(af[mt], bf[nt], acc[mt][nt], 0, 0, 0);
    }
    __syncthreads();
  }

  // LDS-bounce epilogue.
#pragma unroll
  for (int mt = 0; mt < 4; ++mt)
#pragma unroll
    for (int r = 0; r < 4; ++r) {
      const int row = wm + mt * 16 + quad * 4 + r;
#pragma unroll
      for (int nt = 0; nt < 4; ++nt) {
        const int col = wn + nt * 16 + lo;
        float v = acc[mt][nt][r] * scale;
        if (bias) v += bias[n0 + col];
        if (flags & GF_RELU) v = fmaxf(v, 0.f);
        smem[row * 128 + ((((col >> 3) ^ (row & 7)) << 3) | (col & 7))] = f2b(v);
      }
    }
  __syncthreads();
#pragma unroll
  for (int k = 0; k < 8; ++k) {
    const int c = tid + k * 256;
    const int row = c >> 4, c16 = c & 15;
    const short8 v = *(const short8*)(smem + row * 128 + ((c16 ^ (row & 7)) << 3));
    *(short8*)(C + (size_t)(m0 + row) * N + n0 + c16 * 8) = v;
  }
}

// ---------------------------------------------------------------------------
// QKV projection: 2-phase dbuf, dim3 grid (N=1536 -> 12 col tiles). A = bf16 x.
// ---------------------------------------------------------------------------
__global__ __launch_bounds__(256) void gemm_qkv(
    const ushort* __restrict__ A, const ushort* __restrict__ Bt,
    const float* __restrict__ bias, ushort* __restrict__ C)
{
  __shared__ __align__(16) ushort smem[4 * 128 * 64];

  const int bx = blockIdx.x;          // 0..11
  const int by = blockIdx.y;          // 0..127

  const int tid  = threadIdx.x;
  const int w    = tid >> 6;
  const int lane = tid & 63;
  const int lo   = lane & 15;
  const int quad = lane >> 4;
  const int m0   = by * 128;
  const int n0   = bx * 128;
  const int wm   = (w & 1) * 64;
  const int wn   = (w >> 1) * 64;

  const ushort* gaP[4]; const ushort* gbP[4];
#pragma unroll
  for (int k = 0; k < 4; ++k) {
    const int s_ = tid + k * 256;
    const int row = s_ >> 3, sl = s_ & 7;
    gaP[k] = A  + (size_t)(m0 + row) * 512 + ((sl ^ (row & 7)) << 3);
    gbP[k] = Bt + (size_t)(n0 + row) * 512 + ((sl ^ (row & 7)) << 3);
  }

  floatx4 acc[4][4] = {};

#pragma unroll
  for (int k = 0; k < 4; ++k) {
    const int s_ = tid + k * 256;
    __builtin_amdgcn_global_load_lds((const AS1 void*)(gaP[k]), (AS3 void*)(smem + s_ * 8), 16, 0, 0);
    __builtin_amdgcn_global_load_lds((const AS1 void*)(gbP[k]), (AS3 void*)(smem + 8192 + s_ * 8), 16, 0, 0);
  }
  __syncthreads();

  for (int it = 0; it < 8; ++it) {
    const int bo = (it & 1) << 14;
    const ushort* Ac = smem + bo;
    const ushort* Bc = smem + bo + 8192;
    if (it < 7) {
      const int bn = ((it & 1) ^ 1) << 14;
      ushort* An = smem + bn;
      ushort* Bn = smem + bn + 8192;
      const int k0n = (it + 1) * 64;
#pragma unroll
      for (int k = 0; k < 4; ++k) {
        const int s_ = tid + k * 256;
        __builtin_amdgcn_global_load_lds((const AS1 void*)(gaP[k] + k0n), (AS3 void*)(An + s_ * 8), 16, 0, 0);
        __builtin_amdgcn_global_load_lds((const AS1 void*)(gbP[k] + k0n), (AS3 void*)(Bn + s_ * 8), 16, 0, 0);
      }
    }

#pragma unroll
    for (int kk = 0; kk < 2; ++kk) {
      short8 af[4], bf[4];
#pragma unroll
      for (int tt = 0; tt < 4; ++tt) {
        const int ra = wm + tt * 16 + lo;
        const int rb = wn + tt * 16 + lo;
        af[tt] = *(const short8*)(Ac + (size_t)ra * 64 + (((kk * 4 + quad) ^ (ra & 7)) << 3));
        bf[tt] = *(const short8*)(Bc + (size_t)rb * 64 + (((kk * 4 + quad) ^ (rb & 7)) << 3));
      }
#pragma unroll
      for (int mt = 0; mt < 4; ++mt)
#pragma unroll
        for (int nt = 0; nt < 4; ++nt)
          acc[mt][nt] = __builtin_amdgcn_mfma_f32_16x16x32_bf16(af[mt], bf[nt], acc[mt][nt], 0, 0, 0);
    }
    __syncthreads();
  }

#pragma unroll
  for (int mt = 0; mt < 4; ++mt)
#pragma unroll
    for (int r = 0; r < 4; ++r) {
      const int row = wm + mt * 16 + quad * 4 + r;
#pragma unroll
      for (int nt = 0; nt < 4; ++nt) {
        const int col = wn + nt * 16 + lo;
        smem[row * 128 + ((((col >> 3) ^ (row & 7)) << 3) | (col & 7))] =
            f2b(acc[mt][nt][r] + bias[n0 + col]);
      }
    }
  __syncthreads();
#pragma unroll
  for (int k = 0; k < 8; ++k) {
    const int c = tid + k * 256;
    const int row = c >> 4, c16 = c & 15;
    const short8 v = *(const short8*)(smem + row * 128 + ((c16 ^ (row & 7)) << 3));
    *(short8*)(C + (size_t)(m0 + row) * 1536 + n0 + c16 * 8) = v;
  }
}

// x fp32 -> bf16 (pre-cast for QKV GEMM).
__global__ __launch_bounds__(256) void cast_f32_bf16(
    const float* __restrict__ in, ushort* __restrict__ out)
{
  const size_t i = ((size_t)blockIdx.x * 256 + threadIdx.x) * 8;
  const float4 a = *(const float4*)(in + i);
  const float4 b = *(const float4*)(in + i + 4);
  short8 v;
  v[0] = (short)f2b(a.x); v[1] = (short)f2b(a.y);
  v[2] = (short)f2b(a.z); v[3] = (short)f2b(a.w);
  v[4] = (short)f2b(b.x); v[5] = (short)f2b(b.y);
  v[6] = (short)f2b(b.z); v[7] = (short)f2b(b.w);
  *(short8*)(out + i) = v;
}

// ---------------------------------------------------------------------------
__global__ void transpose_cast(const float* __restrict__ in, ushort* __restrict__ out,
                               int R, int C)
{
  __shared__ ushort t[64][65];
  const int r0 = blockIdx.y * 64, c0 = blockIdx.x * 64;
  const int tx = threadIdx.x, ty = threadIdx.y;
  for (int i = ty; i < 64; i += 4)
    t[i][tx] = f2b(in[(size_t)(r0 + i) * C + c0 + tx]);
  __syncthreads();
  for (int i = ty; i < 64; i += 4)
    out[(size_t)(c0 + i) * R + r0 + tx] = t[tx][i];
}

__global__ void concat_bias(const float* __restrict__ a, const float* __restrict__ b,
                            const float* __restrict__ c, float* __restrict__ o)
{
  const int i = blockIdx.x * 256 + threadIdx.x;
  o[i] = (i < 512) ? a[i] : ((i < 1024) ? b[i - 512] : c[i - 1024]);
}

// ---------------------------------------------------------------------------
// out = LayerNorm(X + Y) * g + b. X fp32/bf16, Y bf16, out fp32/bf16.
// ---------------------------------------------------------------------------
__global__ __launch_bounds__(256) void ln_res(
    const void* __restrict__ Xv, int x_f32, const ushort* __restrict__ Y,
    const float* __restrict__ g, const float* __restrict__ b,
    void* __restrict__ outv, int o_f32)
{
  const int w = threadIdx.x >> 6, lane = threadIdx.x & 63;
  const size_t row = (size_t)blockIdx.x * 4 + w;
  const size_t base = row * 512 + lane * 8;

  float v[8];
  if (x_f32) {
    const float* X = (const float*)Xv + base;
    const float4 x0 = *(const float4*)(X), x1 = *(const float4*)(X + 4);
    v[0] = x0.x; v[1] = x0.y; v[2] = x0.z; v[3] = x0.w;
    v[4] = x1.x; v[5] = x1.y; v[6] = x1.z; v[7] = x1.w;
  } else {
    const short8 xv = *(const short8*)((const ushort*)Xv + base);
#pragma unroll
    for (int j = 0; j < 8; ++j) v[j] = b2f((ushort)xv[j]);
  }
  const short8 yv = *(const short8*)(Y + base);
  float s = 0.f, sq = 0.f;
#pragma unroll
  for (int j = 0; j < 8; ++j) {
    v[j] += b2f((ushort)yv[j]);
    s += v[j]; sq += v[j] * v[j];
  }
  for (int m = 1; m < 64; m <<= 1) {
    s  += __shfl_xor(s,  m, 64);
    sq += __shfl_xor(sq, m, 64);
  }
  const float mean = s * (1.f / 512.f);
  const float var  = sq * (1.f / 512.f) - mean * mean;
  const float rstd = rsqrtf(fmaxf(var, 0.f) + 1e-5f);

  const float4 g0 = *(const float4*)(g + lane * 8);
  const float4 g1 = *(const float4*)(g + lane * 8 + 4);
  const float4 b0 = *(const float4*)(b + lane * 8);
  const float4 b1 = *(const float4*)(b + lane * 8 + 4);
  const float gg[8] = {g0.x, g0.y, g0.z, g0.w, g1.x, g1.y, g1.z, g1.w};
  const float bb[8] = {b0.x, b0.y, b0.z, b0.w, b1.x, b1.y, b1.z, b1.w};

  if (o_f32) {
    float* o = (float*)outv + base;
#pragma unroll
    for (int j = 0; j < 8; ++j) o[j] = (v[j] - mean) * rstd * gg[j] + bb[j];
  } else {
    ushort* o = (ushort*)outv + base;
    short8 ov;
#pragma unroll
    for (int j = 0; j < 8; ++j) ov[j] = (short)f2b((v[j] - mean) * rstd * gg[j] + bb[j]);
    *(short8*)o = ov;
  }
}

// ---------------------------------------------------------------------------
extern "C" void kernel_launch(void* const* d_in, const int* in_sizes, int n_in,
                              void* d_out, int out_size, void* d_ws, size_t ws_size,
                              hipStream_t stream)
{
  const float* x    = (const float*)d_in[0];
  const float* Wq_w = (const float*)d_in[1];
  const float* Wq_b = (const float*)d_in[2];
  const float* Wk_w = (const float*)d_in[3];
  const float* Wk_b = (const float*)d_in[4];
  const float* Wv_w = (const float*)d_in[5];
  const float* Wv_b = (const float*)d_in[6];
  const float* Wu_w = (const float*)d_in[7];
  const float* Wu_b = (const float*)d_in[8];
  const float* g1   = (const float*)d_in[9];
  const float* b1   = (const float*)d_in[10];
  const float* f1w  = (const float*)d_in[11];
  const float* f1b  = (const float*)d_in[12];
  const float* f2w  = (const float*)d_in[13];
  const float* f2bv = (const float*)d_in[14];
  const float* g2   = (const float*)d_in[15];
  const float* b2   = (const float*)d_in[16];

  // Workspace (byte offsets; ws >= 224,401,408 B verified).
  char* wsb = (char*)d_ws;
  ushort* wqkvt = (ushort*)(wsb + 0);             // 1536x512   ends   1,572,864
  ushort* wut   = (ushort*)(wsb + 1572864);       //  512x512   ends   2,097,152
  ushort* f1t   = (ushort*)(wsb + 2097152);       // 2048x512   ends   4,194,304
  ushort* f2t   = (ushort*)(wsb + 4194304);       //  512x2048  ends   6,291,456
  float*  bqkv  = (float*) (wsb + 6291456);       // 1536 f32   ends   6,297,600
  ushort* qkv   = (ushort*)(wsb + 6297600);       // 16384x1536 ends  56,629,248
  ushort* vwt   = (ushort*)(wsb + 56629248);      // 4x512x4096 ends  73,406,464
  ushort* uni   = (ushort*)(wsb + 73406464);      // 16384x512  ends  90,183,680
  ushort* h     = (ushort*)(wsb + 106960896);     // 16384x512  ends 123,738,112
  ushort* mid   = (ushort*)(wsb + 123738112);     // 16384x2048 ends 190,846,976
  ushort* ffo   = (ushort*)(wsb + 190846976);     // 16384x512  ends 207,624,192
  ushort* Pbuf  = (ushort*)(wsb + 90183680);      // 134,217,728 B, ends 224,401,408
  ushort* xb    = (ushort*)(wsb + 90183680);      // 16,777,216 B (pre-qk only)

  const dim3 tb(64, 4);
  transpose_cast<<<dim3(8, 8),  tb, 0, stream>>>(Wq_w, wqkvt,              512, 512);
  transpose_cast<<<dim3(8, 8),  tb, 0, stream>>>(Wk_w, wqkvt + 512 * 512,  512, 512);
  transpose_cast<<<dim3(8, 8),  tb, 0, stream>>>(Wv_w, wqkvt + 1024 * 512, 512, 512);
  transpose_cast<<<dim3(8, 8),  tb, 0, stream>>>(Wu_w, wut, 512, 512);
  transpose_cast<<<dim3(32, 8), tb, 0, stream>>>(f1w, f1t, 512, 2048);
  transpose_cast<<<dim3(8, 32), tb, 0, stream>>>(f2w, f2t, 2048, 512);
  concat_bias<<<6, 256, 0, stream>>>(Wq_b, Wk_b, Wv_b, bqkv);

  // Fused QKV: cast x -> bf16, then 2-phase BK=64 GEMM with bounce epilogue.
  cast_f32_bf16<<<4096, 256, 0, stream>>>(x, xb);
  gemm_qkv<<<dim3(12, 128), 256, 0, stream>>>(xb, wqkvt, bqkv, qkv);

  // Attention with fused Wu: VWt -> P -> uni = (P@VWt)/rs + Wu_b (rs inline).
  gemm_vw<<<512, 256, 0, stream>>>(qkv, wut, vwt);
  gemm_qk_exp<<<4096, 256, 0, stream>>>(qkv, Pbuf);
  gemm_pv_wu<<<512, 256, 0, stream>>>(Pbuf, vwt, Wu_b, uni);

  // Residual LN1.
  ln_res<<<4096, 256, 0, stream>>>(x, 1, uni, g1, b1, h, 0);

  // FFN + residual LN2 -> d_out (fp32).
  gemm_async64<<<2048, 256, 0, stream>>>(h, f1t, f1b, mid,
      2048, 512, 512, 512, 4, 7, 1.f, GF_RELU);
  gemm_async64<<<512, 256, 0, stream>>>(mid, f2t, f2bv, ffo,
      512, 2048, 2048, 2048, 2, 7, 1.f, 0);
  ln_res<<<4096, 256, 0, stream>>>(h, 0, ffo, g2, b2, d_out, 1);
}

// Round 12
// 500.481 us; speedup vs baseline: 1.0803x; 1.0803x over previous
//
#include <hip/hip_runtime.h>

#define AS1 __attribute__((address_space(1)))
#define AS3 __attribute__((address_space(3)))

typedef __attribute__((ext_vector_type(8))) short short8;
typedef __attribute__((ext_vector_type(4))) float floatx4;

__device__ __forceinline__ float b2f(ushort u) {
  union { unsigned int i; float f; } x; x.i = ((unsigned int)u) << 16; return x.f;
}
__device__ __forceinline__ ushort f2b(float f) {
  union { float f; unsigned int i; } x; x.f = f;
  unsigned int r = (x.i + 0x7fffu + ((x.i >> 16) & 1u)) >> 16;
  return (ushort)r;
}

#define GF_RELU 1

// ---------------------------------------------------------------------------
// v12 = selective revert of v11 (540us) toward v9 (512us), keeping the one
// proven win:
//  - qk_exp: KEEPS v11's 2-phase dbuf (it left the top-5 -> improved).
//  - pv_wu / FF1/FF2 / qkv: REVERT to v9 1-phase 32KB structures. v11's
//    64KB dbuf halved FF1's blocks/CU (4 -> 2; grid 2048 needs occupancy),
//    costing ~+28us total; pv_wu (2 blk/CU either way, 84% issue-saturated
//    at 790 TF) gained nothing from 2-phase.
// ---------------------------------------------------------------------------

// Pass A: VWt[b][c][j] = sum_d Wu[d][c] * V[b][j][d].  (tiny; BK=32 skeleton)
__global__ __launch_bounds__(256) void gemm_vw(
    const ushort* __restrict__ qkv, const ushort* __restrict__ wut,
    ushort* __restrict__ vwt)
{
  __shared__ __align__(16) ushort As[128 * 32];
  __shared__ __align__(16) ushort Bs[128 * 32];

  const int id = blockIdx.x;
  const int b  = id >> 7;
  const int t  = id & 127;
  const int bx = t & 31;              // j tile
  const int by = t >> 5;              // c tile

  const ushort* A  = wut;
  const ushort* Bt = qkv + (size_t)b * 4096 * 1536 + 1024;
  ushort* C = vwt + (size_t)b * 512 * 4096;

  const int tid  = threadIdx.x;
  const int w    = tid >> 6;
  const int lane = tid & 63;
  const int lo   = lane & 15;
  const int quad = lane >> 4;
  const int m0   = by * 128;
  const int n0   = bx * 128;
  const int wm   = (w & 1) * 64;
  const int wn   = (w >> 1) * 64;

  const int i0 = tid, i1 = tid + 256;
  const ushort* ga0 = A  + (size_t)(m0 + (i0 >> 2)) * 512 + ((i0 & 3) << 3);
  const ushort* ga1 = A  + (size_t)(m0 + (i1 >> 2)) * 512 + ((i1 & 3) << 3);
  const ushort* gb0 = Bt + (size_t)(n0 + (i0 >> 2)) * 1536 + ((i0 & 3) << 3);
  const ushort* gb1 = Bt + (size_t)(n0 + (i1 >> 2)) * 1536 + ((i1 & 3) << 3);

  floatx4 acc[4][4] = {};

  for (int k0 = 0; k0 < 512; k0 += 32) {
    __syncthreads();
    __builtin_amdgcn_global_load_lds((const AS1 void*)(ga0 + k0), (AS3 void*)(As + i0 * 8), 16, 0, 0);
    __builtin_amdgcn_global_load_lds((const AS1 void*)(ga1 + k0), (AS3 void*)(As + i1 * 8), 16, 0, 0);
    __builtin_amdgcn_global_load_lds((const AS1 void*)(gb0 + k0), (AS3 void*)(Bs + i0 * 8), 16, 0, 0);
    __builtin_amdgcn_global_load_lds((const AS1 void*)(gb1 + k0), (AS3 void*)(Bs + i1 * 8), 16, 0, 0);
    __syncthreads();

    short8 af[4], bf[4];
#pragma unroll
    for (int tt = 0; tt < 4; ++tt) {
      af[tt] = *(const short8*)(As + (wm + tt * 16 + lo) * 32 + quad * 8);
      bf[tt] = *(const short8*)(Bs + (wn + tt * 16 + lo) * 32 + quad * 8);
    }
#pragma unroll
    for (int mt = 0; mt < 4; ++mt)
#pragma unroll
      for (int nt = 0; nt < 4; ++nt)
        acc[mt][nt] = __builtin_amdgcn_mfma_f32_16x16x32_bf16(af[mt], bf[nt], acc[mt][nt], 0, 0, 0);
  }

#pragma unroll
  for (int mt = 0; mt < 4; ++mt)
#pragma unroll
    for (int nt = 0; nt < 4; ++nt)
#pragma unroll
      for (int r = 0; r < 4; ++r) {
        const int row = m0 + wm + mt * 16 + quad * 4 + r;
        const int col = n0 + wn + nt * 16 + lo;
        C[(size_t)row * 4096 + col] = f2b(acc[mt][nt][r]);
      }
}

// Pass B: P = exp((Q.K^T)/8). 2-phase dbuf staging (v11-proven) + LDS-bounce
// epilogue. XCD rectangle map (v9-proven): xcd owns (batch, by-half) x all bx.
__global__ __launch_bounds__(256) void gemm_qk_exp(
    const ushort* __restrict__ qkv, ushort* __restrict__ P)
{
  __shared__ __align__(16) ushort smem[4 * 128 * 64];  // buf0 A|B, buf1 A|B

  const int id  = blockIdx.x;         // 0..4095
  const int xcd = id & 7;
  const int s   = id >> 3;            // 0..511
  const int b   = xcd >> 1;           // batch
  const int by  = (xcd & 1) * 16 + (s & 15);
  const int bx  = s >> 4;             // 0..31

  const ushort* A  = qkv + (size_t)b * 4096 * 1536;        // Q rows
  const ushort* Bt = qkv + (size_t)b * 4096 * 1536 + 512;  // K rows
  ushort* C = P + (size_t)b * 4096 * 4096;

  const int tid  = threadIdx.x;
  const int w    = tid >> 6;
  const int lane = tid & 63;
  const int lo   = lane & 15;
  const int quad = lane >> 4;
  const int m0   = by * 128;
  const int n0   = bx * 128;
  const int wm   = (w & 1) * 64;
  const int wn   = (w >> 1) * 64;

  const ushort* gaP[4]; const ushort* gbP[4];
#pragma unroll
  for (int k = 0; k < 4; ++k) {
    const int s_ = tid + k * 256;
    const int row = s_ >> 3, sl = s_ & 7;
    gaP[k] = A  + (size_t)(m0 + row) * 1536 + ((sl ^ (row & 7)) << 3);
    gbP[k] = Bt + (size_t)(n0 + row) * 1536 + ((sl ^ (row & 7)) << 3);
  }

  floatx4 acc[4][4] = {};

  // Prologue: stage tile 0 into buf0.
#pragma unroll
  for (int k = 0; k < 4; ++k) {
    const int s_ = tid + k * 256;
    __builtin_amdgcn_global_load_lds((const AS1 void*)(gaP[k]), (AS3 void*)(smem + s_ * 8), 16, 0, 0);
    __builtin_amdgcn_global_load_lds((const AS1 void*)(gbP[k]), (AS3 void*)(smem + 8192 + s_ * 8), 16, 0, 0);
  }
  __syncthreads();

  for (int it = 0; it < 8; ++it) {
    const int bo = (it & 1) << 14;    // 0 or 16384 (ushort units)
    const ushort* Ac = smem + bo;
    const ushort* Bc = smem + bo + 8192;
    if (it < 7) {                     // issue next-tile stage before compute
      const int bn = ((it & 1) ^ 1) << 14;
      ushort* An = smem + bn;
      ushort* Bn = smem + bn + 8192;
      const int k0n = (it + 1) * 64;
#pragma unroll
      for (int k = 0; k < 4; ++k) {
        const int s_ = tid + k * 256;
        __builtin_amdgcn_global_load_lds((const AS1 void*)(gaP[k] + k0n), (AS3 void*)(An + s_ * 8), 16, 0, 0);
        __builtin_amdgcn_global_load_lds((const AS1 void*)(gbP[k] + k0n), (AS3 void*)(Bn + s_ * 8), 16, 0, 0);
      }
    }

#pragma unroll
    for (int kk = 0; kk < 2; ++kk) {
      short8 af[4], bf[4];
#pragma unroll
      for (int tt = 0; tt < 4; ++tt) {
        const int ra = wm + tt * 16 + lo;
        const int rb = wn + tt * 16 + lo;
        af[tt] = *(const short8*)(Ac + (size_t)ra * 64 + (((kk * 4 + quad) ^ (ra & 7)) << 3));
        bf[tt] = *(const short8*)(Bc + (size_t)rb * 64 + (((kk * 4 + quad) ^ (rb & 7)) << 3));
      }
#pragma unroll
      for (int mt = 0; mt < 4; ++mt)
#pragma unroll
        for (int nt = 0; nt < 4; ++nt)
          acc[mt][nt] = __builtin_amdgcn_mfma_f32_16x16x32_bf16(af[mt], bf[nt], acc[mt][nt], 0, 0, 0);
    }
    __syncthreads();                  // drains next-tile stage; buf reads done
  }

  // LDS-bounce epilogue (aliases stage buffers; all reads complete).
#pragma unroll
  for (int mt = 0; mt < 4; ++mt)
#pragma unroll
    for (int r = 0; r < 4; ++r) {
      const int row = wm + mt * 16 + quad * 4 + r;
#pragma unroll
      for (int nt = 0; nt < 4; ++nt) {
        const int col = wn + nt * 16 + lo;
        smem[row * 128 + ((((col >> 3) ^ (row & 7)) << 3) | (col & 7))] =
            f2b(__expf(acc[mt][nt][r] * 0.125f));
      }
    }
  __syncthreads();
#pragma unroll
  for (int k = 0; k < 8; ++k) {
    const int c = tid + k * 256;
    const int row = c >> 4, c16 = c & 15;
    const short8 v = *(const short8*)(smem + row * 128 + ((c16 ^ (row & 7)) << 3));
    *(short8*)(C + (size_t)(m0 + row) * 4096 + n0 + c16 * 8) = v;
  }
}

// Pass C: uni = (P @ VWt)/rs + Wu_b, rs inline via mfma(af, ones).
// v9 1-phase structure (reverted); XCD-panel swizzle.
__global__ __launch_bounds__(256) void gemm_pv_wu(
    const ushort* __restrict__ P, const ushort* __restrict__ vwt,
    const float* __restrict__ bias, ushort* __restrict__ uni)
{
  __shared__ __align__(16) ushort As[128 * 64];
  __shared__ __align__(16) ushort Bs[128 * 64];
  __shared__ float rsm[128];

  const int id  = blockIdx.x;         // 0..511
  const int xcd = id & 7;
  const int s   = id >> 3;            // 0..63
  const int bx  = s & 3;              // col tile
  const int panel = xcd * 16 + (s >> 2);  // 0..127
  const int b  = panel >> 5;
  const int by = panel & 31;

  const ushort* A  = P   + (size_t)b * 4096 * 4096;
  const ushort* Bt = vwt + (size_t)b * 512 * 4096;

  const int tid  = threadIdx.x;
  const int w    = tid >> 6;
  const int lane = tid & 63;
  const int lo   = lane & 15;
  const int quad = lane >> 4;
  const int m0   = by * 128;
  const int n0   = bx * 128;
  const int wm   = (w & 1) * 64;
  const int wn   = (w >> 1) * 64;

  const ushort* gaP[4]; const ushort* gbP[4];
#pragma unroll
  for (int k = 0; k < 4; ++k) {
    const int s_ = tid + k * 256;
    const int row = s_ >> 3, sl = s_ & 7;
    gaP[k] = A  + (size_t)(m0 + row) * 4096 + ((sl ^ (row & 7)) << 3);
    gbP[k] = Bt + (size_t)(n0 + row) * 4096 + ((sl ^ (row & 7)) << 3);
  }

  short8 ones;
#pragma unroll
  for (int j = 0; j < 8; ++j) ones[j] = (short)0x3F80;  // bf16 1.0

  floatx4 acc[4][4] = {};
  floatx4 rsacc[4] = {};

  for (int k0 = 0; k0 < 4096; k0 += 64) {
    __syncthreads();
#pragma unroll
    for (int k = 0; k < 4; ++k) {
      const int s_ = tid + k * 256;
      __builtin_amdgcn_global_load_lds((const AS1 void*)(gaP[k] + k0), (AS3 void*)(As + s_ * 8), 16, 0, 0);
      __builtin_amdgcn_global_load_lds((const AS1 void*)(gbP[k] + k0), (AS3 void*)(Bs + s_ * 8), 16, 0, 0);
    }
    __syncthreads();

#pragma unroll
    for (int kk = 0; kk < 2; ++kk) {
      short8 af[4], bf[4];
#pragma unroll
      for (int tt = 0; tt < 4; ++tt) {
        const int ra = wm + tt * 16 + lo;
        const int rb = wn + tt * 16 + lo;
        af[tt] = *(const short8*)(As + (size_t)ra * 64 + (((kk * 4 + quad) ^ (ra & 7)) << 3));
        bf[tt] = *(const short8*)(Bs + (size_t)rb * 64 + (((kk * 4 + quad) ^ (rb & 7)) << 3));
      }
#pragma unroll
      for (int tt = 0; tt < 4; ++tt)
        rsacc[tt] = __builtin_amdgcn_mfma_f32_16x16x32_bf16(af[tt], ones, rsacc[tt], 0, 0, 0);
#pragma unroll
      for (int mt = 0; mt < 4; ++mt)
#pragma unroll
        for (int nt = 0; nt < 4; ++nt)
          acc[mt][nt] = __builtin_amdgcn_mfma_f32_16x16x32_bf16(af[mt], bf[nt], acc[mt][nt], 0, 0, 0);
    }
  }

  if (wn == 0 && lo == 0) {
#pragma unroll
    for (int tt = 0; tt < 4; ++tt)
#pragma unroll
      for (int r = 0; r < 4; ++r)
        rsm[wm + tt * 16 + quad * 4 + r] = rsacc[tt][r];
  }
  __syncthreads();

#pragma unroll
  for (int mt = 0; mt < 4; ++mt)
#pragma unroll
    for (int r = 0; r < 4; ++r) {
      const int lrow = wm + mt * 16 + quad * 4 + r;
      const size_t grow = (size_t)b * 4096 + m0 + lrow;
      const float inv = 1.f / rsm[lrow];
#pragma unroll
      for (int nt = 0; nt < 4; ++nt) {
        const int col = n0 + wn + nt * 16 + lo;
        uni[grow * 512 + col] = f2b(acc[mt][nt][r] * inv + bias[col]);
      }
    }
}

// ---------------------------------------------------------------------------
// Async NT GEMM, v9 1-phase BK=64 (32KB LDS, high occupancy for grid-2048
// FF1) + LDS-bounce epilogue, flat grid with XCD swizzle (FF1 / FF2).
// ---------------------------------------------------------------------------
__global__ __launch_bounds__(256) void gemm_async64(
    const ushort* __restrict__ A, const ushort* __restrict__ Bt,
    const float* __restrict__ bias, ushort* __restrict__ C,
    int N, int K, int lda, int ldb,
    int lg_gx, int lg_gy, float scale, int flags)
{
  __shared__ __align__(16) ushort smem[128 * 128];
  ushort* As = smem;
  ushort* Bs = smem + 128 * 64;

  const int id = blockIdx.x;
  const int r8 = id & 7;
  const int s  = id >> 3;
  const int bx = s & ((1 << lg_gx) - 1);
  const int j  = r8 + ((s >> lg_gx) << 3);
  const int by = j & ((1 << lg_gy) - 1);

  const int tid  = threadIdx.x;
  const int w    = tid >> 6;
  const int lane = tid & 63;
  const int lo   = lane & 15;
  const int quad = lane >> 4;
  const int m0   = by * 128;
  const int n0   = bx * 128;
  const int wm   = (w & 1) * 64;
  const int wn   = (w >> 1) * 64;

  const ushort* gaP[4]; const ushort* gbP[4];
#pragma unroll
  for (int k = 0; k < 4; ++k) {
    const int s_ = tid + k * 256;
    const int row = s_ >> 3, sl = s_ & 7;
    gaP[k] = A  + (size_t)(m0 + row) * lda + ((sl ^ (row & 7)) << 3);
    gbP[k] = Bt + (size_t)(n0 + row) * ldb + ((sl ^ (row & 7)) << 3);
  }

  floatx4 acc[4][4] = {};

  for (int k0 = 0; k0 < K; k0 += 64) {
    __syncthreads();
#pragma unroll
    for (int k = 0; k < 4; ++k) {
      const int s_ = tid + k * 256;
      __builtin_amdgcn_global_load_lds((const AS1 void*)(gaP[k] + k0), (AS3 void*)(As + s_ * 8), 16, 0, 0);
      __builtin_amdgcn_global_load_lds((const AS1 void*)(gbP[k] + k0), (AS3 void*)(Bs + s_ * 8), 16, 0, 0);
    }
    __syncthreads();

#pragma unroll
    for (int kk = 0; kk < 2; ++kk) {
      short8 af[4], bf[4];
#pragma unroll
      for (int tt = 0; tt < 4; ++tt) {
        const int ra = wm + tt * 16 + lo;
        const int rb = wn + tt * 16 + lo;
        af[tt] = *(const short8*)(As + (size_t)ra * 64 + (((kk * 4 + quad) ^ (ra & 7)) << 3));
        bf[tt] = *(const short8*)(Bs + (size_t)rb * 64 + (((kk * 4 + quad) ^ (rb & 7)) << 3));
      }
#pragma unroll
      for (int mt = 0; mt < 4; ++mt)
#pragma unroll
        for (int nt = 0; nt < 4; ++nt)
          acc[mt][nt] = __builtin_amdgcn_mfma_f32_16x16x32_bf16(af[mt], bf[nt], acc[mt][nt], 0, 0, 0);
    }
  }

  // LDS-bounce epilogue.
  __syncthreads();
#pragma unroll
  for (int mt = 0; mt < 4; ++mt)
#pragma unroll
    for (int r = 0; r < 4; ++r) {
      const int row = wm + mt * 16 + quad * 4 + r;
#pragma unroll
      for (int nt = 0; nt < 4; ++nt) {
        const int col = wn + nt * 16 + lo;
        float v = acc[mt][nt][r] * scale;
        if (bias) v += bias[n0 + col];
        if (flags & GF_RELU) v = fmaxf(v, 0.f);
        smem[row * 128 + ((((col >> 3) ^ (row & 7)) << 3) | (col & 7))] = f2b(v);
      }
    }
  __syncthreads();
#pragma unroll
  for (int k = 0; k < 8; ++k) {
    const int c = tid + k * 256;
    const int row = c >> 4, c16 = c & 15;
    const short8 v = *(const short8*)(smem + row * 128 + ((c16 ^ (row & 7)) << 3));
    *(short8*)(C + (size_t)(m0 + row) * N + n0 + c16 * 8) = v;
  }
}

// ---------------------------------------------------------------------------
// QKV projection: v9 1-phase, dim3 grid (N=1536 -> 12 col tiles). A = bf16 x.
// ---------------------------------------------------------------------------
__global__ __launch_bounds__(256) void gemm_qkv(
    const ushort* __restrict__ A, const ushort* __restrict__ Bt,
    const float* __restrict__ bias, ushort* __restrict__ C)
{
  __shared__ __align__(16) ushort smem[128 * 128];
  ushort* As = smem;
  ushort* Bs = smem + 128 * 64;

  const int bx = blockIdx.x;          // 0..11
  const int by = blockIdx.y;          // 0..127

  const int tid  = threadIdx.x;
  const int w    = tid >> 6;
  const int lane = tid & 63;
  const int lo   = lane & 15;
  const int quad = lane >> 4;
  const int m0   = by * 128;
  const int n0   = bx * 128;
  const int wm   = (w & 1) * 64;
  const int wn   = (w >> 1) * 64;

  const ushort* gaP[4]; const ushort* gbP[4];
#pragma unroll
  for (int k = 0; k < 4; ++k) {
    const int s_ = tid + k * 256;
    const int row = s_ >> 3, sl = s_ & 7;
    gaP[k] = A  + (size_t)(m0 + row) * 512 + ((sl ^ (row & 7)) << 3);
    gbP[k] = Bt + (size_t)(n0 + row) * 512 + ((sl ^ (row & 7)) << 3);
  }

  floatx4 acc[4][4] = {};

  for (int k0 = 0; k0 < 512; k0 += 64) {
    __syncthreads();
#pragma unroll
    for (int k = 0; k < 4; ++k) {
      const int s_ = tid + k * 256;
      __builtin_amdgcn_global_load_lds((const AS1 void*)(gaP[k] + k0), (AS3 void*)(As + s_ * 8), 16, 0, 0);
      __builtin_amdgcn_global_load_lds((const AS1 void*)(gbP[k] + k0), (AS3 void*)(Bs + s_ * 8), 16, 0, 0);
    }
    __syncthreads();

#pragma unroll
    for (int kk = 0; kk < 2; ++kk) {
      short8 af[4], bf[4];
#pragma unroll
      for (int tt = 0; tt < 4; ++tt) {
        const int ra = wm + tt * 16 + lo;
        const int rb = wn + tt * 16 + lo;
        af[tt] = *(const short8*)(As + (size_t)ra * 64 + (((kk * 4 + quad) ^ (ra & 7)) << 3));
        bf[tt] = *(const short8*)(Bs + (size_t)rb * 64 + (((kk * 4 + quad) ^ (rb & 7)) << 3));
      }
#pragma unroll
      for (int mt = 0; mt < 4; ++mt)
#pragma unroll
        for (int nt = 0; nt < 4; ++nt)
          acc[mt][nt] = __builtin_amdgcn_mfma_f32_16x16x32_bf16(af[mt], bf[nt], acc[mt][nt], 0, 0, 0);
    }
  }

  __syncthreads();
#pragma unroll
  for (int mt = 0; mt < 4; ++mt)
#pragma unroll
    for (int r = 0; r < 4; ++r) {
      const int row = wm + mt * 16 + quad * 4 + r;
#pragma unroll
      for (int nt = 0; nt < 4; ++nt) {
        const int col = wn + nt * 16 + lo;
        smem[row * 128 + ((((col >> 3) ^ (row & 7)) << 3) | (col & 7))] =
            f2b(acc[mt][nt][r] + bias[n0 + col]);
      }
    }
  __syncthreads();
#pragma unroll
  for (int k = 0; k < 8; ++k) {
    const int c = tid + k * 256;
    const int row = c >> 4, c16 = c & 15;
    const short8 v = *(const short8*)(smem + row * 128 + ((c16 ^ (row & 7)) << 3));
    *(short8*)(C + (size_t)(m0 + row) * 1536 + n0 + c16 * 8) = v;
  }
}

// x fp32 -> bf16 (pre-cast for QKV GEMM).
__global__ __launch_bounds__(256) void cast_f32_bf16(
    const float* __restrict__ in, ushort* __restrict__ out)
{
  const size_t i = ((size_t)blockIdx.x * 256 + threadIdx.x) * 8;
  const float4 a = *(const float4*)(in + i);
  const float4 b = *(const float4*)(in + i + 4);
  short8 v;
  v[0] = (short)f2b(a.x); v[1] = (short)f2b(a.y);
  v[2] = (short)f2b(a.z); v[3] = (short)f2b(a.w);
  v[4] = (short)f2b(b.x); v[5] = (short)f2b(b.y);
  v[6] = (short)f2b(b.z); v[7] = (short)f2b(b.w);
  *(short8*)(out + i) = v;
}

// ---------------------------------------------------------------------------
__global__ void transpose_cast(const float* __restrict__ in, ushort* __restrict__ out,
                               int R, int C)
{
  __shared__ ushort t[64][65];
  const int r0 = blockIdx.y * 64, c0 = blockIdx.x * 64;
  const int tx = threadIdx.x, ty = threadIdx.y;
  for (int i = ty; i < 64; i += 4)
    t[i][tx] = f2b(in[(size_t)(r0 + i) * C + c0 + tx]);
  __syncthreads();
  for (int i = ty; i < 64; i += 4)
    out[(size_t)(c0 + i) * R + r0 + tx] = t[tx][i];
}

__global__ void concat_bias(const float* __restrict__ a, const float* __restrict__ b,
                            const float* __restrict__ c, float* __restrict__ o)
{
  const int i = blockIdx.x * 256 + threadIdx.x;
  o[i] = (i < 512) ? a[i] : ((i < 1024) ? b[i - 512] : c[i - 1024]);
}

// ---------------------------------------------------------------------------
// out = LayerNorm(X + Y) * g + b. X fp32/bf16, Y bf16, out fp32/bf16.
// ---------------------------------------------------------------------------
__global__ __launch_bounds__(256) void ln_res(
    const void* __restrict__ Xv, int x_f32, const ushort* __restrict__ Y,
    const float* __restrict__ g, const float* __restrict__ b,
    void* __restrict__ outv, int o_f32)
{
  const int w = threadIdx.x >> 6, lane = threadIdx.x & 63;
  const size_t row = (size_t)blockIdx.x * 4 + w;
  const size_t base = row * 512 + lane * 8;

  float v[8];
  if (x_f32) {
    const float* X = (const float*)Xv + base;
    const float4 x0 = *(const float4*)(X), x1 = *(const float4*)(X + 4);
    v[0] = x0.x; v[1] = x0.y; v[2] = x0.z; v[3] = x0.w;
    v[4] = x1.x; v[5] = x1.y; v[6] = x1.z; v[7] = x1.w;
  } else {
    const short8 xv = *(const short8*)((const ushort*)Xv + base);
#pragma unroll
    for (int j = 0; j < 8; ++j) v[j] = b2f((ushort)xv[j]);
  }
  const short8 yv = *(const short8*)(Y + base);
  float s = 0.f, sq = 0.f;
#pragma unroll
  for (int j = 0; j < 8; ++j) {
    v[j] += b2f((ushort)yv[j]);
    s += v[j]; sq += v[j] * v[j];
  }
  for (int m = 1; m < 64; m <<= 1) {
    s  += __shfl_xor(s,  m, 64);
    sq += __shfl_xor(sq, m, 64);
  }
  const float mean = s * (1.f / 512.f);
  const float var  = sq * (1.f / 512.f) - mean * mean;
  const float rstd = rsqrtf(fmaxf(var, 0.f) + 1e-5f);

  const float4 g0 = *(const float4*)(g + lane * 8);
  const float4 g1 = *(const float4*)(g + lane * 8 + 4);
  const float4 b0 = *(const float4*)(b + lane * 8);
  const float4 b1 = *(const float4*)(b + lane * 8 + 4);
  const float gg[8] = {g0.x, g0.y, g0.z, g0.w, g1.x, g1.y, g1.z, g1.w};
  const float bb[8] = {b0.x, b0.y, b0.z, b0.w, b1.x, b1.y, b1.z, b1.w};

  if (o_f32) {
    float* o = (float*)outv + base;
#pragma unroll
    for (int j = 0; j < 8; ++j) o[j] = (v[j] - mean) * rstd * gg[j] + bb[j];
  } else {
    ushort* o = (ushort*)outv + base;
    short8 ov;
#pragma unroll
    for (int j = 0; j < 8; ++j) ov[j] = (short)f2b((v[j] - mean) * rstd * gg[j] + bb[j]);
    *(short8*)o = ov;
  }
}

// ---------------------------------------------------------------------------
extern "C" void kernel_launch(void* const* d_in, const int* in_sizes, int n_in,
                              void* d_out, int out_size, void* d_ws, size_t ws_size,
                              hipStream_t stream)
{
  const float* x    = (const float*)d_in[0];
  const float* Wq_w = (const float*)d_in[1];
  const float* Wq_b = (const float*)d_in[2];
  const float* Wk_w = (const float*)d_in[3];
  const float* Wk_b = (const float*)d_in[4];
  const float* Wv_w = (const float*)d_in[5];
  const float* Wv_b = (const float*)d_in[6];
  const float* Wu_w = (const float*)d_in[7];
  const float* Wu_b = (const float*)d_in[8];
  const float* g1   = (const float*)d_in[9];
  const float* b1   = (const float*)d_in[10];
  const float* f1w  = (const float*)d_in[11];
  const float* f1b  = (const float*)d_in[12];
  const float* f2w  = (const float*)d_in[13];
  const float* f2bv = (const float*)d_in[14];
  const float* g2   = (const float*)d_in[15];
  const float* b2   = (const float*)d_in[16];

  // Workspace (byte offsets; ws >= 224,401,408 B verified).
  char* wsb = (char*)d_ws;
  ushort* wqkvt = (ushort*)(wsb + 0);             // 1536x512   ends   1,572,864
  ushort* wut   = (ushort*)(wsb + 1572864);       //  512x512   ends   2,097,152
  ushort* f1t   = (ushort*)(wsb + 2097152);       // 2048x512   ends   4,194,304
  ushort* f2t   = (ushort*)(wsb + 4194304);       //  512x2048  ends   6,291,456
  float*  bqkv  = (float*) (wsb + 6291456);       // 1536 f32   ends   6,297,600
  ushort* qkv   = (ushort*)(wsb + 6297600);       // 16384x1536 ends  56,629,248
  ushort* vwt   = (ushort*)(wsb + 56629248);      // 4x512x4096 ends  73,406,464
  ushort* uni   = (ushort*)(wsb + 73406464);      // 16384x512  ends  90,183,680
  ushort* h     = (ushort*)(wsb + 106960896);     // 16384x512  ends 123,738,112
  ushort* mid   = (ushort*)(wsb + 123738112);     // 16384x2048 ends 190,846,976
  ushort* ffo   = (ushort*)(wsb + 190846976);     // 16384x512  ends 207,624,192
  ushort* Pbuf  = (ushort*)(wsb + 90183680);      // 134,217,728 B, ends 224,401,408
  ushort* xb    = (ushort*)(wsb + 90183680);      // 16,777,216 B (pre-qk only)

  const dim3 tb(64, 4);
  transpose_cast<<<dim3(8, 8),  tb, 0, stream>>>(Wq_w, wqkvt,              512, 512);
  transpose_cast<<<dim3(8, 8),  tb, 0, stream>>>(Wk_w, wqkvt + 512 * 512,  512, 512);
  transpose_cast<<<dim3(8, 8),  tb, 0, stream>>>(Wv_w, wqkvt + 1024 * 512, 512, 512);
  transpose_cast<<<dim3(8, 8),  tb, 0, stream>>>(Wu_w, wut, 512, 512);
  transpose_cast<<<dim3(32, 8), tb, 0, stream>>>(f1w, f1t, 512, 2048);
  transpose_cast<<<dim3(8, 32), tb, 0, stream>>>(f2w, f2t, 2048, 512);
  concat_bias<<<6, 256, 0, stream>>>(Wq_b, Wk_b, Wv_b, bqkv);

  // Fused QKV: cast x -> bf16, then 1-phase BK=64 GEMM with bounce epilogue.
  cast_f32_bf16<<<4096, 256, 0, stream>>>(x, xb);
  gemm_qkv<<<dim3(12, 128), 256, 0, stream>>>(xb, wqkvt, bqkv, qkv);

  // Attention with fused Wu: VWt -> P -> uni = (P@VWt)/rs + Wu_b (rs inline).
  gemm_vw<<<512, 256, 0, stream>>>(qkv, wut, vwt);
  gemm_qk_exp<<<4096, 256, 0, stream>>>(qkv, Pbuf);
  gemm_pv_wu<<<512, 256, 0, stream>>>(Pbuf, vwt, Wu_b, uni);

  // Residual LN1.
  ln_res<<<4096, 256, 0, stream>>>(x, 1, uni, g1, b1, h, 0);

  // FFN + residual LN2 -> d_out (fp32).
  gemm_async64<<<2048, 256, 0, stream>>>(h, f1t, f1b, mid,
      2048, 512, 512, 512, 4, 7, 1.f, GF_RELU);
  gemm_async64<<<512, 256, 0, stream>>>(mid, f2t, f2bv, ffo,
      512, 2048, 2048, 2048, 2, 7, 1.f, 0);
  ln_res<<<4096, 256, 0, stream>>>(h, 0, ffo, g2, b2, d_out, 1);
}